// Round 1
// 116.037 us; speedup vs baseline: 1.0273x; 1.0273x over previous
//
#include <hip/hip_runtime.h>

#define NIMG 4
#define NCLS 19
#define CCH  32
#define LH   128
#define LW   128
#define HH   512
#define WW   512
#define HWQ  (LH*LW)    // 16384 low-res pixels
#define HWP  (HH*WW)    // 262144 hi-res pixels

// k_field tiling: each block OWNS a disjoint TRxTC low-res region
#define TR 8
#define TC 16
#define NTX (LW/TC)       // 8
#define NTY (LH/TR)       // 16
#define NTILE (NTY*NTX)   // 128 blocks per image
#define TCELLS (TR*TC)    // 128
#define HALO_R (TR*4+4)   // 36
#define HALO_C (TC*4+4)   // 68

#define NCHUNK 4          // channel chunks for k_gram (8 ch each)
#define GPLANES 5         // self, h, v, d, a

// Bilinear taps for 128 -> 512, half-pixel convention. Edge taps are shifted to
// a valid (b, b+1) pair with weights {1,0}/{0,1} (exact dyadic, same math).
__device__ __forceinline__ void taps(int v, int lim, int& i0, float& w0, float& w1) {
    int r = v & 3;
    int b = (v >> 2) + ((r < 2) ? -1 : 0);
    float f = 0.125f + 0.25f * (float)((r + 2) & 3);   // r: 0->.625 1->.875 2->.125 3->.375
    w0 = 1.f - f; w1 = f;
    if (b < 0)           { b = 0;       w0 = 1.f; w1 = 0.f; }
    else if (b >= lim)   { b = lim - 1; w0 = 0.f; w1 = 1.f; }
    i0 = b;
}

// K0: Gram planes per (img, channel-chunk): for each low-res cell (y,x)
//   g0=<E[y,x],E[y,x]> g1=<.,E[y,x+1]> g2=<.,E[y+1,x]> g3=<.,E[y+1,x+1]> g4=<E[y,x+1],E[y+1,x]>
// over 8 channels. 1024 blocks -> 4 waves/SIMD, coalesced row loads + shuffles.
__global__ __launch_bounds__(256) void k_gram(const float* __restrict__ E,
                                              float* __restrict__ G) {
    int n = blockIdx.y;
    int chunk = blockIdx.x >> 6;        // 0..3
    int rp    = blockIdx.x & 63;        // row pair
    int x  = threadIdx.x & 127;
    int dy = threadIdx.x >> 7;
    int y  = rp * 2 + dy;
    int yp = (y < LH - 1) ? y + 1 : y;
    int xp = (x < LW - 1) ? x + 1 : x;
    bool lane63 = ((x & 63) == 63);
    const float* Ep = E + ((size_t)n * CCH + chunk * 8) * HWQ;
    float g0 = 0.f, g1 = 0.f, g2 = 0.f, g3 = 0.f, g4 = 0.f;
#pragma unroll
    for (int c = 0; c < 8; c++) {
        float a  = Ep[y * LW + x];
        float b  = Ep[yp * LW + x];
        float ar = __shfl_down(a, 1);
        float br = __shfl_down(b, 1);
        if (lane63) { ar = Ep[y * LW + xp]; br = Ep[yp * LW + xp]; }
        g0 = fmaf(a, a,  g0);
        g1 = fmaf(a, ar, g1);
        g2 = fmaf(a, b,  g2);
        g3 = fmaf(a, br, g3);
        g4 = fmaf(ar, b, g4);
        Ep += HWQ;
    }
    float* Gp = G + (((size_t)n * NCHUNK + chunk) * GPLANES) * HWQ + y * LW + x;
    Gp[0]       = g0;
    Gp[HWQ]     = g1;
    Gp[2 * HWQ] = g2;
    Gp[3 * HWQ] = g3;
    Gp[4 * HWQ] = g4;
}

// K1: per-tile A-field in LDS + fused contract + per-pixel S2 via Gram planes.
//   P_sum[n][tile][k][c] = sum_{cells} A[k][cell] * E[c][cell]
//   P_cnt[n][tile][k]    = sum_{cells} A[k][cell]
//   P_S2 [n][tile][k]    = sum_{owned pixels of class k} ||v_p||^2
__global__ __launch_bounds__(256) void k_field(const float* __restrict__ E,
        const int* __restrict__ lab, const float* __restrict__ G,
        float* __restrict__ P_sum, float* __restrict__ P_cnt, float* __restrict__ P_S2) {
    int tile = blockIdx.x, n = blockIdx.y;
    int ty = tile >> 3, tx = tile & 7;          // NTX=8
    int Y0 = ty * TR, X0 = tx * TC;
    __shared__ float A[TCELLS * NCLS];          // [cell][k], stride 19
    __shared__ float red[8 * NCLS * CCH];       // [g][k][c] contract partials
    __shared__ float Gt[4 * 10 * 18];           // planes: Gs, Gh, Gv, Gd+Ga (tile+ring)
    __shared__ float S2b[NCLS];
    int tid = threadIdx.x;
    for (int i = tid; i < TCELLS * NCLS; i += 256) A[i] = 0.f;
    if (tid < NCLS) S2b[tid] = 0.f;

    // stage Gram tile (rows Y0-1..Y0+8, cols X0-1..X0+16; sum the 4 channel chunks)
    const float* Gn = G + (size_t)n * (NCHUNK * GPLANES * HWQ);
    for (int i = tid; i < 4 * 180; i += 256) {
        int p = i / 180, r = i % 180, gy = r / 18, gx = r % 18;
        int yy = Y0 - 1 + gy; yy = yy < 0 ? 0 : (yy > LH - 1 ? LH - 1 : yy);
        int xx = X0 - 1 + gx; xx = xx < 0 ? 0 : (xx > LW - 1 ? LW - 1 : xx);
        int off = yy * LW + xx;
        float s;
        if (p < 3) {
            s = Gn[(0 * GPLANES + p) * HWQ + off] + Gn[(1 * GPLANES + p) * HWQ + off]
              + Gn[(2 * GPLANES + p) * HWQ + off] + Gn[(3 * GPLANES + p) * HWQ + off];
        } else {
            s = 0.f;
#pragma unroll
            for (int ch = 0; ch < 4; ch++)
                s += Gn[(ch * GPLANES + 3) * HWQ + off] + Gn[(ch * GPLANES + 4) * HWQ + off];
        }
        Gt[i] = s;
    }
    __syncthreads();

    // halo pass: A-field taps (all halo pixels) + S2 (owned pixels only)
    const int* ln = lab + (size_t)n * HWP;
    int h_lo = Y0 * 4 - 2, w_lo = X0 * 4 - 2;
    for (int i = tid; i < HALO_R * HALO_C; i += 256) {
        int hr = i / HALO_C, wc = i - hr * HALO_C;
        int h = h_lo + hr, w = w_lo + wc;
        if (h < 0 || h >= HH || w < 0 || w >= WW) continue;
        int L = ln[h * WW + w];
        int y0, x0; float wy0, wy1, wx0, wx1;
        taps(h, LH - 1, y0, wy0, wy1);
        taps(w, LW - 1, x0, wx0, wx1);
        int ry = y0 - Y0, rx = x0 - X0;
        if (ry >= 0 && ry < TR) {
            if (rx >= 0 && rx < TC)         atomicAdd(&A[(ry * TC + rx) * NCLS + L], wy0 * wx0);
            if (rx + 1 >= 0 && rx + 1 < TC) atomicAdd(&A[(ry * TC + rx + 1) * NCLS + L], wy0 * wx1);
        }
        if (ry + 1 >= 0 && ry + 1 < TR) {
            if (rx >= 0 && rx < TC)         atomicAdd(&A[((ry + 1) * TC + rx) * NCLS + L], wy1 * wx0);
            if (rx + 1 >= 0 && rx + 1 < TC) atomicAdd(&A[((ry + 1) * TC + rx + 1) * NCLS + L], wy1 * wx1);
        }
        if (h >= Y0 * 4 && h < Y0 * 4 + TR * 4 && w >= X0 * 4 && w < X0 * 4 + TC * 4) {
            int gy = y0 - (Y0 - 1), gx = x0 - (X0 - 1);
            int g00 = gy * 18 + gx;
            float u0 = wy0 * wy0, u1 = wy1 * wy1, u2 = wy0 * wy1;
            float s0 = wx0 * wx0, s1 = wx1 * wx1, s2 = wx0 * wx1;
            float d2 =
                u0 * (s0 * Gt[g00]      + s1 * Gt[g00 + 1]  + 2.f * s2 * Gt[180 + g00])
              + u1 * (s0 * Gt[g00 + 18] + s1 * Gt[g00 + 19] + 2.f * s2 * Gt[180 + g00 + 18])
              + 2.f * u2 * (s0 * Gt[360 + g00] + s1 * Gt[360 + g00 + 1] + s2 * Gt[540 + g00]);
            atomicAdd(&S2b[L], d2);
        }
    }
    __syncthreads();

    // fused contract: thread (g,c); A reads are (half-)wave-uniform broadcasts
    int g = tid >> 5, c = tid & 31;
    const float* Ec = E + ((size_t)n * CCH + c) * HWQ;
    float acc[NCLS];
#pragma unroll
    for (int k = 0; k < NCLS; k++) acc[k] = 0.f;
#pragma unroll
    for (int j = 0; j < TCELLS / 8; j++) {
        int cell = g * (TCELLS / 8) + j;
        int cy = cell >> 4, cx = cell & 15;     // TC=16
        float e = Ec[(Y0 + cy) * LW + (X0 + cx)];
        const float* Ar = &A[cell * NCLS];
#pragma unroll
        for (int k = 0; k < NCLS; k++) acc[k] = fmaf(Ar[k], e, acc[k]);
    }
#pragma unroll
    for (int k = 0; k < NCLS; k++) red[(g * NCLS + k) * CCH + c] = acc[k];
    __syncthreads();

    float* Ps = P_sum + (size_t)(n * NTILE + tile) * (NCLS * CCH);
    for (int idx = tid; idx < NCLS * CCH; idx += 256) {
        float s = 0.f;
#pragma unroll
        for (int gg = 0; gg < 8; gg++) s += red[gg * NCLS * CCH + idx];
        Ps[idx] = s;
    }
    if (tid < NCLS) {
        float s = 0.f;
        for (int cell = 0; cell < TCELLS; cell++) s += A[cell * NCLS + tid];
        P_cnt[(size_t)(n * NTILE + tile) * NCLS + tid] = s;
        P_S2[(size_t)(n * NTILE + tile) * NCLS + tid] = S2b[tid];
    }
}

// K3: reduce partials, intra via S2 - 2 m.s + cnt |m|^2, inter pairwise, output
__global__ __launch_bounds__(384) void k_final(const float* __restrict__ P_sum,
        const float* __restrict__ P_cnt, const float* __restrict__ P_S2,
        float* __restrict__ out) {
    int n = blockIdx.x, t = threadIdx.x;
    __shared__ float csum[NCLS * 33];   // stride-33 pad
    __shared__ float m[NCLS * 33];
    __shared__ float cnt[NCLS];
    __shared__ float S2[NCLS];
    __shared__ float rk1[NCLS * 17];
    __shared__ float rk2[NCLS * 17];
    __shared__ float sIntra, sNfg, sInter;

    if (t == 0) sInter = 0.f;
    if (t < 304) {                       // 19 classes x 16 groups, 8 tiles each
        int k = t >> 4, gg = t & 15;
        const float* p1 = P_cnt + ((size_t)n * NTILE + gg * 8) * NCLS + k;
        const float* p2 = P_S2  + ((size_t)n * NTILE + gg * 8) * NCLS + k;
        float s1 = 0.f, s2 = 0.f;
#pragma unroll
        for (int j = 0; j < 8; j++) { s1 += p1[j * NCLS]; s2 += p2[j * NCLS]; }
        rk1[k * 17 + gg] = s1; rk2[k * 17 + gg] = s2;
    }
    for (int idx = t; idx < NCLS * CCH; idx += 384) {
        float s = 0.f;
        const float* p = P_sum + (size_t)n * NTILE * NCLS * CCH + idx;
        for (int b = 0; b < NTILE; b++) s += p[b * NCLS * CCH];
        csum[(idx >> 5) * 33 + (idx & 31)] = s;
    }
    __syncthreads();
    if (t < NCLS) {
        float s1 = 0.f, s2 = 0.f;
        for (int gg = 0; gg < 16; gg++) { s1 += rk1[t * 17 + gg]; s2 += rk2[t * 17 + gg]; }
        cnt[t] = s1; S2[t] = s2;
    }
    __syncthreads();
    for (int idx = t; idx < NCLS * CCH; idx += 384) {
        int k = idx >> 5, c = idx & 31;
        m[k * 33 + c] = csum[k * 33 + c] / (cnt[k] + 1.f);
    }
    __syncthreads();

    // intra + n_fg (all of t<19 sits in wave 0)
    float vi = 0.f, fg = 0.f;
    if (t >= 1 && t < NCLS && cnt[t] > 0.f) {
        fg = 1.f;
        float dot = 0.f, mm = 0.f;
        for (int c = 0; c < CCH; c++) {
            float mv = m[t * 33 + c];
            dot = fmaf(mv, csum[t * 33 + c], dot);
            mm = fmaf(mv, mv, mm);
        }
        vi = (S2[t] - 2.f * dot + cnt[t] * mm) * (1.f / 32.f) / (cnt[t] + 1.f);
    }
#pragma unroll
    for (int s_ = 32; s_ >= 1; s_ >>= 1) { vi += __shfl_xor(vi, s_); fg += __shfl_xor(fg, s_); }
    if (t == 0) { sIntra = vi; sNfg = fg; }

    // inter: 18x18 foreground pairs
    float ve = 0.f;
    if (t < 324) {
        int j = 1 + t / 18, k = 1 + t % 18;
        if (cnt[j] > 0.f && cnt[k] > 0.f) {
            float s = 0.f;
            for (int c = 0; c < CCH; c++) {
                float d = m[j * 33 + c] - m[k * 33 + c];
                s = fmaf(d, d, s);
            }
            ve = s * (1.f / 32.f);
        }
    }
#pragma unroll
    for (int s_ = 32; s_ >= 1; s_ >>= 1) ve += __shfl_xor(ve, s_);
    if ((t & 63) == 0) atomicAdd(&sInter, ve);
    __syncthreads();
    if (t == 0) out[n] = sIntra / sNfg - sInter / (sNfg * sNfg);
}

extern "C" void kernel_launch(void* const* d_in, const int* in_sizes, int n_in,
                              void* d_out, int out_size, void* d_ws, size_t ws_size,
                              hipStream_t stream) {
    const float* E = (const float*)d_in[0];   // (4,32,128,128) fp32
    const int* lab = (const int*)d_in[1];     // (4,512,512) int
    float* out = (float*)d_out;               // (4,) fp32

    float* ws = (float*)d_ws;
    float* P_sum = ws;                                        // 4*128*608
    float* P_cnt = P_sum + (size_t)NIMG * NTILE * NCLS * CCH; // 4*128*19
    float* P_S2  = P_cnt + (size_t)NIMG * NTILE * NCLS;       // 4*128*19
    float* G     = P_S2  + (size_t)NIMG * NTILE * NCLS;       // 4*4*5*16384
    // all slots fully overwritten every call -> no memset needed

    k_gram <<<dim3(256, NIMG),   dim3(256), 0, stream>>>(E, G);
    k_field<<<dim3(NTILE, NIMG), dim3(256), 0, stream>>>(E, lab, G, P_sum, P_cnt, P_S2);
    k_final<<<dim3(NIMG),        dim3(384), 0, stream>>>(P_sum, P_cnt, P_S2, out);
}